// Round 1
// baseline (2113.067 us; speedup 1.0000x reference)
//
#include <hip/hip_runtime.h>

typedef int v4i __attribute__((ext_vector_type(4)));

// ws layout (bytes)
#define WMAX_OFF   0
#define CNT_OFF    4
#define EP_OFF     8         // u32 rolling epoch (persists across launches/replays)
#define IMEM_OFF   64        // float[500*64]
#define PK_OFF     131072    // u32[2*4096] untagged spike packets (2 batches/word), double-buffered
#define FLAGS_OFF  196608    // u32[2*128]  per-block ready flags, double-buffered
#define WFRAG_OFF  262144    // v4i[8192*64] quantized i8 hi/lo W fragments (8 MB)

__global__ void sr_prep(const float* __restrict__ x, const float* __restrict__ w_in,
                        float* __restrict__ imem, unsigned* wmax_bits, unsigned* cnt,
                        unsigned* ep) {
  int b = threadIdx.x;
  if (b == 64) *wmax_bits = 0u;
  if (b == 65) *cnt = 0u;
  if (b == 66) *ep += 1024u;   // fresh tag space every launch / graph replay
  if (b < 64) {
    float wi = w_in[0];
    float im = 0.0f;
    for (int t = 0; t < 500; ++t) {
      im = 0.8f * im + x[b * 500 + t] * wi;   // input LIF (Vmem mode, no reset)
      imem[t * 64 + b] = im;
    }
  }
}

__global__ void sr_wmax(const float* __restrict__ W, unsigned* wmax_bits) {
  __shared__ unsigned sm;
  if (threadIdx.x == 0) sm = 0u;
  __syncthreads();
  float m = 0.0f;
  for (size_t i = (size_t)blockIdx.x * 256 + threadIdx.x; i < 4194304ull; i += 262144ull)
    m = fmaxf(m, fabsf(W[i]));
  atomicMax(&sm, __float_as_uint(m));   // floats >=0: uint order == float order
  __syncthreads();
  if (threadIdx.x == 0) atomicMax(wmax_bits, sm);
}

// Quantize W to 16-bit fixed point (hi*256+lo i8 planes) laid out as MFMA B-fragments.
// k-slot (q, d, i) of wave-w/frag-kl  <->  neuron m = (16w + 4kl + q)*16 + 4i + d.
__global__ void sr_wquant(const float* __restrict__ W, const unsigned* __restrict__ wmax_bits,
                          v4i* __restrict__ wfr) {
  __shared__ float ws[16][257];
  const int p = blockIdx.x >> 3;     // 0..127 (16-neuron slice)
  const int w = blockIdx.x & 7;      // wave / K-slice [256w, 256w+256)
  const int tid = threadIdx.x;       // 512
  {
    int r = tid >> 5;                // 16 rows
    int c0 = (tid & 31) * 8;         // 8 floats each, coalesced
    const float* src = W + (size_t)(p * 16 + r) * 2048 + 256 * w + c0;
    #pragma unroll
    for (int j = 0; j < 8; ++j) ws[r][c0 + j] = src[j];
  }
  __syncthreads();
  const int fl = tid >> 6;           // 0..7 : kl = fl>>1, sp = fl&1
  const int kl = fl >> 1, sp = fl & 1;
  const int lane = tid & 63;
  const int col = lane & 15;         // output neuron (local)
  const int q = lane >> 4;
  const float S = 32000.0f / __uint_as_float(*wmax_bits);
  int dw[4] = {0, 0, 0, 0};
  #pragma unroll
  for (int j = 0; j < 16; ++j) {
    int d = j >> 2, i = j & 3;
    float wv = ws[col][(4 * kl + q) * 16 + 4 * i + d];
    int qv = (int)rintf(wv * S);     // |qv| <= 32000
    int hi = (qv + 128) >> 8;        // i8 range
    int lo = qv - (hi << 8);         // i8 range; hi*256+lo == qv exactly
    int v = sp ? lo : hi;
    dw[d] |= (v & 255) << (8 * i);
  }
  v4i o; o[0] = dw[0]; o[1] = dw[1]; o[2] = dw[2]; o[3] = dw[3];
  wfr[(size_t)((((p * 8 + w) * 4 + kl) * 2 + sp)) * 64 + lane] = o;
}

// Persistent dataflow kernel: 128 blocks (16 neurons each) x 512 threads (8 waves).
// Per step: poll 128 per-block flags (512 B), bulk-read 16 KB packed spike payload once,
// LDS spike table (XOR-swizzled), 32 i8 MFMAs/wave, exact int32 LDS K-reduce,
// fp32 epilogue, publish packets -> barrier(vmcnt drain) -> publish flag -> records.
__global__ __launch_bounds__(512, 2)
void sr_main(const float* __restrict__ imem, const v4i* __restrict__ wfr,
             unsigned* pk, unsigned* flags, const unsigned* __restrict__ ep,
             const float* __restrict__ w_res, const unsigned* __restrict__ wmax_bits,
             unsigned* cnt_g, float* __restrict__ out) {
  extern __shared__ char smem_raw[];
  unsigned* spk_lds = (unsigned*)smem_raw;            // [4096] u32 = 16KB
  v4i* redv = (v4i*)(smem_raw + 16384);               // [32][64] v4i = 32KB (disjoint)
  int* outl = (int*)(smem_raw + 49152);               // [1024] int = 4KB

  const int p = blockIdx.x;          // 0..127
  const int tid = threadIdx.x;
  const int w = tid >> 6;            // wave = K-slice [256w, 256w+256)
  const int lane = tid & 63;
  const int q = lane >> 4;
  const int col = lane & 15;
  const unsigned base = *ep;         // this launch's tag base

  // resident W fragments: 8 x v4i = 32 VGPRs
  v4i wf[4][2];
  #pragma unroll
  for (int kl = 0; kl < 4; ++kl)
    #pragma unroll
    for (int sp = 0; sp < 2; ++sp)
      wf[kl][sp] = wfr[(size_t)((((p * 8 + w) * 4 + kl) * 2 + sp)) * 64 + lane];

  // epilogue ownership: thread -> batch be, neurons {16p + nl, +1}
  const int be = tid >> 3;
  const int h = tid & 7;
  const int nl = h * 2;
  const float wr0 = w_res[p * 16 + nl + 0];
  const float wr1 = w_res[p * 16 + nl + 1];
  float mem0 = 0, mem1 = 0, sp0 = 0, sp1 = 0;
  int cnt = 0;
  const float invS = __uint_as_float(*wmax_bits) / 32000.0f;
  const v4i vzero = {0, 0, 0, 0};
  // packet bit layout: neuron n (local 0..15), batch-parity pe: bit = 8*(n>>2)+(n&3)+4*pe
  const int pubshift = (h >> 1) * 8 + 2 * (h & 1) + 4 * (be & 1);
  const int sh2 = (col & 1) * 4;     // consumer batch-parity shift
  const int cc = col >> 1;

  for (int t = 0; t < 500; ++t) {
    float im = imem[t * 64 + be];    // independent load, overlaps poll
    float rec0 = 0, rec1 = 0;
    if (t > 0) {
      // ---- phase 1: poll 128 per-block flags (exact match, epoch-rolled) ----
      const unsigned target = base + (unsigned)t;
      if (tid < 128) {
        unsigned* fp = flags + (size_t)(t & 1) * 128 + tid;
        int guard = 0;
        while (__hip_atomic_load(fp, __ATOMIC_RELAXED, __HIP_MEMORY_SCOPE_AGENT) != target) {
          __builtin_amdgcn_s_sleep(1);
          if (++guard > (1 << 20)) break;   // hang safety
        }
      }
      __syncthreads();  // F1: all 128 source blocks have published

      // ---- phase 2: bulk-read 4096-word payload once; XOR-swizzled LDS table ----
      {
        const unsigned* src = pk + (size_t)(t & 1) * 4096 + tid;
        unsigned qw[8];
        #pragma unroll
        for (int j = 0; j < 8; ++j)
          qw[j] = __hip_atomic_load(src + 512 * j, __ATOMIC_RELAXED, __HIP_MEMORY_SCOPE_AGENT);
        #pragma unroll
        for (int j = 0; j < 8; ++j) {
          int P = tid + 512 * j;     // P = psrc*32 + bpair
          int idx = (P & ~31) | ((P & 31) ^ (((P >> 5) & 3) << 3));
          spk_lds[idx] = qw[j];
        }
      }
      __syncthreads();  // B1: spike table ready

      // per-lane A words: 16 ds_read_b32, conflict-free (32 banks covered via q-XOR)
      unsigned ww[16];
      #pragma unroll
      for (int f = 0; f < 16; ++f) {
        int kl = f & 3, bt = f >> 2;
        ww[f] = spk_lds[(16 * w + 4 * kl + q) * 32 + ((bt * 8 + cc) ^ (q << 3))];
      }
      // no barrier needed: spk_lds next written after F1/B1 of step t+1; redv disjoint

      v4i acc[4][2];
      #pragma unroll
      for (int bt = 0; bt < 4; ++bt) { acc[bt][0] = vzero; acc[bt][1] = vzero; }
      #pragma unroll
      for (int f = 0; f < 16; ++f) {
        int kl = f & 3, bt = f >> 2;
        unsigned wbs = ww[f] >> sh2;     // select batch parity once
        v4i a;  // byte i of a[d] = bit (8i+d) = neuron (4i+d) of this 16-group
        a[0] = (int)((wbs >> 0) & 0x01010101u);
        a[1] = (int)((wbs >> 1) & 0x01010101u);
        a[2] = (int)((wbs >> 2) & 0x01010101u);
        a[3] = (int)((wbs >> 3) & 0x01010101u);
        acc[bt][0] = __builtin_amdgcn_mfma_i32_16x16x64_i8(a, wf[kl][0], acc[bt][0], 0, 0, 0);
        acc[bt][1] = __builtin_amdgcn_mfma_i32_16x16x64_i8(a, wf[kl][1], acc[bt][1], 0, 0, 0);
      }
      // combine planes exactly; write K-partials
      #pragma unroll
      for (int bt = 0; bt < 4; ++bt) {
        v4i c = acc[bt][0] * 256 + acc[bt][1];
        redv[(w * 4 + bt) * 64 + lane] = c;   // contiguous b128
      }
      __syncthreads();  // B3
      if (w < 4) {      // wave v reduces tile bt=v over 8 K-slices
        v4i s = vzero;
        #pragma unroll
        for (int ww2 = 0; ww2 < 8; ++ww2) s += redv[(ww2 * 4 + w) * 64 + lane];
        // C/D layout: col=lane&15 (neuron), row=(lane>>4)*4+reg (batch)
        int ob = (w * 16 + (lane >> 4) * 4) * 16 + (lane & 15);
        outl[ob]      = s[0];
        outl[ob + 16] = s[1];
        outl[ob + 32] = s[2];
        outl[ob + 48] = s[3];
      }
      __syncthreads();  // B4: outl ready
      int2 rv = *(const int2*)(outl + be * 16 + nl);
      rec0 = (float)rv.x * invS;
      rec1 = (float)rv.y * invS;
    }

    // epilogue, reference op order: mem = 0.9*mem*(1-spk) + cur + rec
    mem0 = 0.9f * mem0 * (1.0f - sp0) + im * wr0 + rec0;
    mem1 = 0.9f * mem1 * (1.0f - sp1) + im * wr1 + rec1;
    int s0i = mem0 > 1.0f, s1i = mem1 > 1.0f;
    sp0 = (float)s0i; sp1 = (float)s1i;

    // publish packets FIRST (critical path): 16-thread OR -> one u32 per batch-pair
    unsigned v = ((unsigned)(s0i | (s1i << 1))) << pubshift;
    v |= (unsigned)__shfl_xor((int)v, 1);
    v |= (unsigned)__shfl_xor((int)v, 2);
    v |= (unsigned)__shfl_xor((int)v, 4);
    v |= (unsigned)__shfl_xor((int)v, 8);
    if ((tid & 15) == 0)
      __hip_atomic_store(&pk[(size_t)((t + 1) & 1) * 4096 + p * 32 + (tid >> 4)], v,
                         __ATOMIC_RELAXED, __HIP_MEMORY_SCOPE_AGENT);
    __syncthreads();  // P1: compiler drains vmcnt(0) per wave before s_barrier -> all packets visible
    if (tid == 0)
      __hip_atomic_store(&flags[(size_t)((t + 1) & 1) * 128 + p], base + (unsigned)(t + 1),
                         __ATOMIC_RELAXED, __HIP_MEMORY_SCOPE_AGENT);
    cnt += s0i + s1i;

    // records after publish (off critical path)
    size_t sb = 1ull + (size_t)t * 131072ull + (size_t)be * 2048ull + (size_t)(p * 16 + nl);
    __builtin_nontemporal_store(sp0, out + sb + 0);
    __builtin_nontemporal_store(sp1, out + sb + 1);
    __builtin_nontemporal_store(mem0, out + sb + 65536000ull + 0);
    __builtin_nontemporal_store(mem1, out + sb + 65536000ull + 1);
  }

  // firing-rate count: one global atomic per block
  __syncthreads();
  int* csh = (int*)smem_raw;
  if (tid == 0) csh[0] = 0;
  __syncthreads();
  atomicAdd(csh, cnt);
  __syncthreads();
  if (tid == 0) atomicAdd(cnt_g, (unsigned)csh[0]);
}

__global__ void sr_fin(const unsigned* __restrict__ cnt, float* __restrict__ out) {
  out[0] = (float)((double)(*cnt) / 65536000.0);
}

extern "C" void kernel_launch(void* const* d_in, const int* in_sizes, int n_in,
                              void* d_out, int out_size, void* d_ws, size_t ws_size,
                              hipStream_t stream) {
  const float* x     = (const float*)d_in[0];  // (64,500,1)
  const float* w_in  = (const float*)d_in[1];  // (1,1)
  const float* w_res = (const float*)d_in[2];  // (2048,1)
  const float* W     = (const float*)d_in[3];  // (2048,2048)
  float* out = (float*)d_out;
  char* ws = (char*)d_ws;

  unsigned* wmax_bits = (unsigned*)(ws + WMAX_OFF);
  unsigned* cntp      = (unsigned*)(ws + CNT_OFF);
  unsigned* ep        = (unsigned*)(ws + EP_OFF);
  float* imem         = (float*)(ws + IMEM_OFF);
  unsigned* pkt       = (unsigned*)(ws + PK_OFF);
  unsigned* flg       = (unsigned*)(ws + FLAGS_OFF);
  v4i* wfr            = (v4i*)(ws + WFRAG_OFF);

  sr_prep<<<1, 128, 0, stream>>>(x, w_in, imem, wmax_bits, cntp, ep);
  sr_wmax<<<1024, 256, 0, stream>>>(W, wmax_bits);
  sr_wquant<<<1024, 512, 0, stream>>>(W, wmax_bits, wfr);
  sr_main<<<128, 512, 53248, stream>>>(imem, wfr, pkt, flg, ep, w_res, wmax_bits, cntp, out);
  sr_fin<<<1, 1, 0, stream>>>(cntp, out);
}